// Round 4
// baseline (141.437 us; speedup 1.0000x reference)
//
#include <hip/hip_runtime.h>
#include <hip/hip_bf16.h>

typedef __bf16 bf16x8 __attribute__((ext_vector_type(8)));
typedef float  f32x4  __attribute__((ext_vector_type(4)));

#define NN 4096
#define DK 128
#define BM 128
#define BN 128
#define NT 8            // y-tiles swept per block (1024 output cols)
#define NMAX 0.99f

__global__ __launch_bounds__(512, 4)
void hyp_dist_kernel(const float* __restrict__ X, const float* __restrict__ Y,
                     float* __restrict__ Out)
{
    __shared__ alignas(16) __bf16 aL[BM * DK];   // 32 KB, x-tile (staged once)
    __shared__ alignas(16) __bf16 bL[BN * DK];   // 32 KB, y-tile (re-staged per sweep step)
    __shared__ float xsL[BM];
    __shared__ float ysL[BN];

    const int tid   = threadIdx.x;
    const int bz    = blockIdx.z;
    const int brow  = blockIdx.y * BM;
    const int bcol0 = blockIdx.x * (BN * NT);

    const float* xb  = X + ((size_t)bz * NN + brow) * DK;
    const float* yb0 = Y + ((size_t)bz * NN + bcol0) * DK;

    const int c16 = tid & 15;   // 16B (8-elem) chunk within a row
    const int rr  = tid >> 4;   // 32 rows per pass (512 threads)

    // ---- Stage x-tile once: f32 -> bf16 LDS (swizzled) + row sum-of-squares.
#pragma unroll
    for (int p = 0; p < 4; ++p) {
        const int r = p * 32 + rr;
        const f32x4* s4 = (const f32x4*)(xb + r * DK + c16 * 8);
        f32x4 v0 = s4[0], v1 = s4[1];
        float s = v0[0]*v0[0] + v0[1]*v0[1] + v0[2]*v0[2] + v0[3]*v0[3]
                + v1[0]*v1[0] + v1[1]*v1[1] + v1[2]*v1[2] + v1[3]*v1[3];
        s += __shfl_xor(s, 1);
        s += __shfl_xor(s, 2);
        s += __shfl_xor(s, 4);
        s += __shfl_xor(s, 8);
        if (c16 == 0) xsL[r] = s;
        bf16x8 pk;
        pk[0]=(__bf16)v0[0]; pk[1]=(__bf16)v0[1]; pk[2]=(__bf16)v0[2]; pk[3]=(__bf16)v0[3];
        pk[4]=(__bf16)v1[0]; pk[5]=(__bf16)v1[1]; pk[6]=(__bf16)v1[2]; pk[7]=(__bf16)v1[3];
        const int byt = (r * 256 + c16 * 16) ^ ((r & 7) << 4);
        *(bf16x8*)((char*)aL + byt) = pk;
    }
    // ---- Stage y-tile 0 the same way.
#pragma unroll
    for (int p = 0; p < 4; ++p) {
        const int r = p * 32 + rr;
        const f32x4* s4 = (const f32x4*)(yb0 + r * DK + c16 * 8);
        f32x4 v0 = s4[0], v1 = s4[1];
        float s = v0[0]*v0[0] + v0[1]*v0[1] + v0[2]*v0[2] + v0[3]*v0[3]
                + v1[0]*v1[0] + v1[1]*v1[1] + v1[2]*v1[2] + v1[3]*v1[3];
        s += __shfl_xor(s, 1);
        s += __shfl_xor(s, 2);
        s += __shfl_xor(s, 4);
        s += __shfl_xor(s, 8);
        if (c16 == 0) ysL[r] = s;
        bf16x8 pk;
        pk[0]=(__bf16)v0[0]; pk[1]=(__bf16)v0[1]; pk[2]=(__bf16)v0[2]; pk[3]=(__bf16)v0[3];
        pk[4]=(__bf16)v1[0]; pk[5]=(__bf16)v1[1]; pk[6]=(__bf16)v1[2]; pk[7]=(__bf16)v1[3];
        const int byt = (r * 256 + c16 * 16) ^ ((r & 7) << 4);
        *(bf16x8*)((char*)bL + byt) = pk;
    }
    __syncthreads();

    const int lane = tid & 63;
    const int wid  = tid >> 6;   // 8 waves: 2 (rows) x 4 (cols)
    const int wm   = wid >> 2;   // 64 output rows per wave
    const int wn   = wid & 3;    // 32 output cols per wave
    const int r16  = lane & 15;
    const int kg   = lane >> 4;

    const float* ob = nullptr;   // silence unused warnings pattern; real ptr below
    float* obase = Out + ((size_t)bz * NN + brow) * NN + bcol0;
    (void)ob;

    f32x4 yreg[8];

    for (int t = 0; t < NT; ++t) {
        // ---- Prefetch next y-tile into registers (latency hides under
        //      MFMA + epilogue; consumed after the post-store barrier).
        if (t + 1 < NT) {
            const float* yn = yb0 + (size_t)(t + 1) * BN * DK;
#pragma unroll
            for (int p = 0; p < 4; ++p) {
                const f32x4* s4 = (const f32x4*)(yn + (p * 32 + rr) * DK + c16 * 8);
                yreg[2 * p]     = s4[0];
                yreg[2 * p + 1] = s4[1];
            }
        }

        // ---- MFMA on current y-tile.
        f32x4 acc[4][2] = {};
#pragma unroll
        for (int ks = 0; ks < 4; ++ks) {
            const int kb = ks * 32 + kg * 8;
            bf16x8 af[4], bg[2];
#pragma unroll
            for (int i = 0; i < 4; ++i) {
                const int r = wm * 64 + i * 16 + r16;
                const int byt = (r * 256 + kb * 2) ^ ((r & 7) << 4);
                af[i] = *(const bf16x8*)((const char*)aL + byt);
            }
#pragma unroll
            for (int j = 0; j < 2; ++j) {
                const int r = wn * 32 + j * 16 + r16;
                const int byt = (r * 256 + kb * 2) ^ ((r & 7) << 4);
                bg[j] = *(const bf16x8*)((const char*)bL + byt);
            }
            // A=y-frag, B=x-frag: lane's 4 acc regs = 4 consecutive output
            // columns of one output row -> f32x4 stores.
#pragma unroll
            for (int i = 0; i < 4; ++i)
#pragma unroll
                for (int j = 0; j < 2; ++j)
                    acc[i][j] = __builtin_amdgcn_mfma_f32_16x16x32_bf16(bg[j], af[i], acc[i][j], 0, 0, 0);
        }

        // ---- Epilogue. num_sq = den * s, s = xs + ys - 2*dot,
        //      diff_norm = s * rsqrt(s*den); out = ln((1+dn)/(1-dn)).
        float* otile = obase + t * BN;
#pragma unroll
        for (int i = 0; i < 4; ++i) {
            const int r = wm * 64 + i * 16 + r16;
            const float u = xsL[r];
            float* orow = otile + (size_t)r * NN;
#pragma unroll
            for (int j = 0; j < 2; ++j) {
                const int cb = wn * 32 + j * 16 + kg * 4;
                const f32x4 v4 = *(const f32x4*)&ysL[cb];
                f32x4 o4;
#pragma unroll
                for (int q = 0; q < 4; ++q) {
                    const float d  = acc[i][j][q];
                    const float v  = v4[q];
                    const float e1 = fmaf(-2.0f, d, 1.0f);
                    const float den = fmaf(u, v, e1);
                    float s = fmaf(-2.0f, d, u + v);
                    s = fmaxf(s, 1e-12f);
                    const float dn0 = s * __builtin_amdgcn_rsqf(s * den);
                    const float dn = fminf(dn0, NMAX);
                    o4[q] = __logf((1.0f + dn) * __builtin_amdgcn_rcpf(1.0f - dn));
                }
                *(f32x4*)(orow + cb) = o4;
            }
        }

        __syncthreads();   // all waves done reading bL for tile t

        // ---- Write prefetched y-tile into LDS (convert + reduce).
        if (t + 1 < NT) {
#pragma unroll
            for (int p = 0; p < 4; ++p) {
                const int r = p * 32 + rr;
                f32x4 v0 = yreg[2 * p], v1 = yreg[2 * p + 1];
                float s = v0[0]*v0[0] + v0[1]*v0[1] + v0[2]*v0[2] + v0[3]*v0[3]
                        + v1[0]*v1[0] + v1[1]*v1[1] + v1[2]*v1[2] + v1[3]*v1[3];
                s += __shfl_xor(s, 1);
                s += __shfl_xor(s, 2);
                s += __shfl_xor(s, 4);
                s += __shfl_xor(s, 8);
                if (c16 == 0) ysL[r] = s;
                bf16x8 pk;
                pk[0]=(__bf16)v0[0]; pk[1]=(__bf16)v0[1]; pk[2]=(__bf16)v0[2]; pk[3]=(__bf16)v0[3];
                pk[4]=(__bf16)v1[0]; pk[5]=(__bf16)v1[1]; pk[6]=(__bf16)v1[2]; pk[7]=(__bf16)v1[3];
                const int byt = (r * 256 + c16 * 16) ^ ((r & 7) << 4);
                *(bf16x8*)((char*)bL + byt) = pk;
            }
            __syncthreads();
        }
    }
}

extern "C" void kernel_launch(void* const* d_in, const int* in_sizes, int n_in,
                              void* d_out, int out_size, void* d_ws, size_t ws_size,
                              hipStream_t stream) {
    const float* X = (const float*)d_in[0];
    const float* Y = (const float*)d_in[1];
    float* O = (float*)d_out;
    const int b = in_sizes[0] / (NN * DK);   // = 4
    dim3 grid(NN / (BN * NT), NN / BM, b);
    hyp_dist_kernel<<<grid, dim3(512), 0, stream>>>(X, Y, O);
}

// Round 5
// 104.022 us; speedup vs baseline: 1.3597x; 1.3597x over previous
//
#include <hip/hip_runtime.h>
#include <hip/hip_bf16.h>

typedef __bf16 bf16x8 __attribute__((ext_vector_type(8)));
typedef float  f32x4  __attribute__((ext_vector_type(4)));

#define NN 4096
#define DK 128
#define BM 128
#define BN 64
#define NMAX 0.99f

__global__ __launch_bounds__(512, 6)
void hyp_dist_kernel(const float* __restrict__ X, const float* __restrict__ Y,
                     float* __restrict__ Out)
{
    __shared__ alignas(16) __bf16 aL[BM * DK];   // 32 KB
    __shared__ alignas(16) __bf16 bL[BN * DK];   // 16 KB
    __shared__ float xsL[BM];
    __shared__ float ysL[BN];

    const int tid  = threadIdx.x;
    const int bz   = blockIdx.z;
    const int brow = blockIdx.y * BM;
    const int bcol = blockIdx.x * BN;

    const float* xb = X + ((size_t)bz * NN + brow) * DK;
    const float* yb = Y + ((size_t)bz * NN + bcol) * DK;

    const int c16 = tid & 15;   // 16B (8-elem) chunk within a row
    const int rr  = tid >> 4;   // 32 rows per pass (512 threads)

    // Stage x-tile (128 rows): f32 -> bf16 LDS (swizzled) + row sum-of-squares.
#pragma unroll
    for (int p = 0; p < 4; ++p) {
        const int r = p * 32 + rr;
        const f32x4* s4 = (const f32x4*)(xb + r * DK + c16 * 8);
        f32x4 v0 = s4[0], v1 = s4[1];
        float s = v0[0]*v0[0] + v0[1]*v0[1] + v0[2]*v0[2] + v0[3]*v0[3]
                + v1[0]*v1[0] + v1[1]*v1[1] + v1[2]*v1[2] + v1[3]*v1[3];
        s += __shfl_xor(s, 1);
        s += __shfl_xor(s, 2);
        s += __shfl_xor(s, 4);
        s += __shfl_xor(s, 8);
        if (c16 == 0) xsL[r] = s;
        bf16x8 pk;
        pk[0]=(__bf16)v0[0]; pk[1]=(__bf16)v0[1]; pk[2]=(__bf16)v0[2]; pk[3]=(__bf16)v0[3];
        pk[4]=(__bf16)v1[0]; pk[5]=(__bf16)v1[1]; pk[6]=(__bf16)v1[2]; pk[7]=(__bf16)v1[3];
        const int byt = (r * 256 + c16 * 16) ^ ((r & 7) << 4);
        *(bf16x8*)((char*)aL + byt) = pk;
    }
    // Stage y-tile (64 rows).
#pragma unroll
    for (int p = 0; p < 2; ++p) {
        const int r = p * 32 + rr;
        const f32x4* s4 = (const f32x4*)(yb + r * DK + c16 * 8);
        f32x4 v0 = s4[0], v1 = s4[1];
        float s = v0[0]*v0[0] + v0[1]*v0[1] + v0[2]*v0[2] + v0[3]*v0[3]
                + v1[0]*v1[0] + v1[1]*v1[1] + v1[2]*v1[2] + v1[3]*v1[3];
        s += __shfl_xor(s, 1);
        s += __shfl_xor(s, 2);
        s += __shfl_xor(s, 4);
        s += __shfl_xor(s, 8);
        if (c16 == 0) ysL[r] = s;
        bf16x8 pk;
        pk[0]=(__bf16)v0[0]; pk[1]=(__bf16)v0[1]; pk[2]=(__bf16)v0[2]; pk[3]=(__bf16)v0[3];
        pk[4]=(__bf16)v1[0]; pk[5]=(__bf16)v1[1]; pk[6]=(__bf16)v1[2]; pk[7]=(__bf16)v1[3];
        const int byt = (r * 256 + c16 * 16) ^ ((r & 7) << 4);
        *(bf16x8*)((char*)bL + byt) = pk;
    }
    __syncthreads();

    const int lane = tid & 63;
    const int wid  = tid >> 6;   // 8 waves: 4 (rows) x 2 (cols)
    const int wm   = wid >> 1;   // 32 output rows per wave
    const int wn   = wid & 1;    // 32 output cols per wave
    const int r16  = lane & 15;
    const int kg   = lane >> 4;

    f32x4 acc[2][2] = {};

#pragma unroll
    for (int ks = 0; ks < 4; ++ks) {
        const int kb = ks * 32 + kg * 8;     // element k-offset for this lane
        bf16x8 af[2], bg[2];
#pragma unroll
        for (int i = 0; i < 2; ++i) {
            const int r = wm * 32 + i * 16 + r16;
            const int byt = (r * 256 + kb * 2) ^ ((r & 7) << 4);
            af[i] = *(const bf16x8*)((const char*)aL + byt);
        }
#pragma unroll
        for (int j = 0; j < 2; ++j) {
            const int r = wn * 32 + j * 16 + r16;
            const int byt = (r * 256 + kb * 2) ^ ((r & 7) << 4);
            bg[j] = *(const bf16x8*)((const char*)bL + byt);
        }
        // A=y-frag, B=x-frag: lane's 4 acc regs = 4 consecutive output
        // columns of one output row -> f32x4 stores.
#pragma unroll
        for (int i = 0; i < 2; ++i)
#pragma unroll
            for (int j = 0; j < 2; ++j)
                acc[i][j] = __builtin_amdgcn_mfma_f32_16x16x32_bf16(bg[j], af[i], acc[i][j], 0, 0, 0);
    }

    // Epilogue. num_sq = den * s with s = xs + ys - 2*dot,
    // diff_norm = s * rsqrt(s*den); out = ln((1+dn)/(1-dn)).
    float* ob = Out + ((size_t)bz * NN + brow) * NN + bcol;
#pragma unroll
    for (int i = 0; i < 2; ++i) {
        const int r = wm * 32 + i * 16 + r16;
        const float u = xsL[r];
        float* orow = ob + (size_t)r * NN;
#pragma unroll
        for (int j = 0; j < 2; ++j) {
            const int cb = wn * 32 + j * 16 + kg * 4;
            const f32x4 v4 = *(const f32x4*)&ysL[cb];
            f32x4 o4;
#pragma unroll
            for (int q = 0; q < 4; ++q) {
                const float d  = acc[i][j][q];
                const float v  = v4[q];
                const float e1 = fmaf(-2.0f, d, 1.0f);      // 1 - 2d
                const float den = fmaf(u, v, e1);           // 1 - 2d + u*v
                float s = fmaf(-2.0f, d, u + v);            // u + v - 2d
                s = fmaxf(s, 1e-12f);
                const float dn0 = s * __builtin_amdgcn_rsqf(s * den);
                const float dn = fminf(dn0, NMAX);
                o4[q] = __logf((1.0f + dn) * __builtin_amdgcn_rcpf(1.0f - dn));
            }
            *(f32x4*)(orow + cb) = o4;
        }
    }
}

extern "C" void kernel_launch(void* const* d_in, const int* in_sizes, int n_in,
                              void* d_out, int out_size, void* d_ws, size_t ws_size,
                              hipStream_t stream) {
    const float* X = (const float*)d_in[0];
    const float* Y = (const float*)d_in[1];
    float* O = (float*)d_out;
    const int b = in_sizes[0] / (NN * DK);   // = 4
    dim3 grid(NN / BN, NN / BM, b);
    hyp_dist_kernel<<<grid, dim3(512), 0, stream>>>(X, Y, O);
}